// Round 1
// baseline (472.774 us; speedup 1.0000x reference)
//
#include <hip/hip_runtime.h>
#include <hip/hip_bf16.h>
#include <stdint.h>

#define B_ 4
#define S_ 2048
#define D_ 1024
#define F_ 4096
#define E_ 8
#define CAP_ 320
#define BS_ (B_*S_)      // 8192 tokens
#define MPE 1280         // B_*CAP_ rows per expert

typedef unsigned short u16;
typedef __attribute__((ext_vector_type(8))) short bf16x8;
typedef __attribute__((ext_vector_type(4))) float f32x4;
typedef __attribute__((ext_vector_type(4))) unsigned short u16x4;

__device__ __forceinline__ u16 f2bf(float f) {
  union { float f; uint32_t u; } v; v.f = f;
  uint32_t r = (v.u + 0x7FFFu + ((v.u >> 16) & 1u)) >> 16;
  return (u16)r;
}

__device__ __forceinline__ void gload16(const void* g, void* l) {
  __builtin_amdgcn_global_load_lds(
      (const __attribute__((address_space(1))) uint32_t*)g,
      (__attribute__((address_space(3))) uint32_t*)l, 16, 0, 0);
}

// ---------------------------------------------------------------------------
// Router: logits (f64 accum), softmax max-prob, argmax, and out = maxp * hs
// one wave per token, 4 tokens per block
// ---------------------------------------------------------------------------
__global__ __launch_bounds__(256) void router_kernel(
    const float* __restrict__ hs, const float* __restrict__ rw,
    float* __restrict__ out, float* __restrict__ logits,
    float* __restrict__ maxp, int* __restrict__ eidx)
{
  const int wv = threadIdx.x >> 6, l = threadIdx.x & 63;
  const int token = blockIdx.x * 4 + wv;
  const float* row = hs + (size_t)token * D_;
  const float4* rw4 = (const float4*)rw;

  double acc0=0, acc1=0, acc2=0, acc3=0, acc4=0, acc5=0, acc6=0, acc7=0;
  float4 v[4];
#pragma unroll
  for (int j = 0; j < 4; ++j) {
    const int d4 = l + j * 64;
    v[j] = ((const float4*)row)[d4];
#pragma unroll
    for (int c = 0; c < 4; ++c) {
      const int d = d4 * 4 + c;
      const float x = (&v[j].x)[c];
      const float4 w0 = rw4[d * 2];
      const float4 w1 = rw4[d * 2 + 1];
      acc0 += (double)x * (double)w0.x;
      acc1 += (double)x * (double)w0.y;
      acc2 += (double)x * (double)w0.z;
      acc3 += (double)x * (double)w0.w;
      acc4 += (double)x * (double)w1.x;
      acc5 += (double)x * (double)w1.y;
      acc6 += (double)x * (double)w1.z;
      acc7 += (double)x * (double)w1.w;
    }
  }
  double acc[E_] = {acc0, acc1, acc2, acc3, acc4, acc5, acc6, acc7};
#pragma unroll
  for (int e = 0; e < E_; ++e) {
#pragma unroll
    for (int off = 32; off; off >>= 1)
      acc[e] += __shfl_xor(acc[e], off);
  }
  float lg[E_];
#pragma unroll
  for (int e = 0; e < E_; ++e) lg[e] = (float)acc[e];

  float lmax = lg[0]; int am = 0;
#pragma unroll
  for (int e = 1; e < E_; ++e) { if (lg[e] > lmax) { lmax = lg[e]; am = e; } }
  float sum = 0.f;
#pragma unroll
  for (int e = 0; e < E_; ++e) sum += expf(lg[e] - lmax);
  const float mp = 1.0f / sum;   // max softmax prob

  float* orow = out + (size_t)token * D_;
#pragma unroll
  for (int j = 0; j < 4; ++j) {
    float4 o;
    o.x = v[j].x * mp; o.y = v[j].y * mp; o.z = v[j].z * mp; o.w = v[j].w * mp;
    ((float4*)orow)[l + j * 64] = o;
  }
  if (l == 0) {
#pragma unroll
    for (int e = 0; e < E_; ++e) logits[(size_t)token * E_ + e] = lg[e];
    maxp[token] = mp;
    eidx[token] = am;
  }
}

// ---------------------------------------------------------------------------
// Capacity scan: one block per (b,e); sequence-ordered rank via block scan
// ---------------------------------------------------------------------------
__global__ __launch_bounds__(256) void scan_kernel(
    const int* __restrict__ eidx, int* __restrict__ tok,
    float* __restrict__ eout)
{
  const int b = blockIdx.x >> 3, e = blockIdx.x & 7;
  __shared__ int wsum[4];
  const int tid = threadIdx.x, wv = tid >> 6, l = tid & 63;
  int base = 0;
  for (int ch = 0; ch < S_ / 256; ++ch) {
    const int s = ch * 256 + tid;
    const bool p = (eidx[b * S_ + s] == e);
    const unsigned long long m = __ballot(p);
    const int lp = __popcll(m & ((1ULL << l) - 1ULL));
    if (l == 0) wsum[wv] = __popcll(m);
    __syncthreads();
    int pre = 0, tot = 0;
#pragma unroll
    for (int w = 0; w < 4; ++w) { if (w < wv) pre += wsum[w]; tot += wsum[w]; }
    if (p) {
      const int rank = base + pre + lp;
      if (rank < CAP_) tok[(b * E_ + e) * CAP_ + rank] = s;
      eout[b * S_ + s] = (rank < CAP_) ? (float)e : 0.0f;
    }
    base += tot;
    __syncthreads();
  }
}

// ---------------------------------------------------------------------------
// Transpose+convert: W[e][K][N] f32 -> WT[e][N][K] bf16
// ---------------------------------------------------------------------------
__global__ __launch_bounds__(256) void transpose_kernel(
    const float* __restrict__ W, u16* __restrict__ WT, int K, int N)
{
  __shared__ float tile[32][33];
  const int tiles_k = K >> 5, tiles_n = N >> 5;
  const int e = blockIdx.x / (tiles_k * tiles_n);
  const int r = blockIdx.x % (tiles_k * tiles_n);
  const int k0 = (r / tiles_n) << 5, n0 = (r % tiles_n) << 5;
  const int tx = threadIdx.x & 31, ty = threadIdx.x >> 5;
  const float* We = W + (size_t)e * K * N;
  u16* WTe = WT + (size_t)e * K * N;
#pragma unroll
  for (int i = 0; i < 4; ++i)
    tile[ty + i * 8][tx] = We[(size_t)(k0 + ty + i * 8) * N + (n0 + tx)];
  __syncthreads();
#pragma unroll
  for (int i = 0; i < 4; ++i) {
    const int n = n0 + ty + i * 8, k = k0 + tx;
    WTe[(size_t)n * K + k] = f2bf(tile[tx][ty + i * 8]);
  }
}

// ---------------------------------------------------------------------------
// Gather routed tokens -> Xg[e][b*CAP+c][D] bf16 (zeros for empty slots)
// ---------------------------------------------------------------------------
__global__ __launch_bounds__(256) void gather_kernel(
    const float* __restrict__ hs, const int* __restrict__ tok,
    u16* __restrict__ Xg)
{
  const int bx = blockIdx.x;            // e*MPE + r
  const int e = bx / MPE, r = bx % MPE;
  const int b = r / CAP_, c = r % CAP_;
  const int t = tok[(b * E_ + e) * CAP_ + c];
  const int d = threadIdx.x * 4;
  u16x4 o;
  if (t >= 0) {
    const float4 vv = *(const float4*)(hs + ((size_t)(b * S_ + t)) * D_ + d);
    o[0] = f2bf(vv.x); o[1] = f2bf(vv.y); o[2] = f2bf(vv.z); o[3] = f2bf(vv.w);
  } else {
    o[0] = 0; o[1] = 0; o[2] = 0; o[3] = 0;
  }
  *(u16x4*)(Xg + (size_t)bx * D_ + d) = o;
}

// ---------------------------------------------------------------------------
// Grouped GEMM, 128x128 tile, BK=64, 4 waves (2x2), mfma 16x16x32 bf16.
// A[e][MPE][K] bf16, Bt[e][N][K] bf16 (pre-transposed).
// MODE 1: hg = relu(A@B) -> bf16.  MODE 2: scatter out = maxp * (A@B).
// ---------------------------------------------------------------------------
template<int MODE>
__global__ __launch_bounds__(256) void moe_gemm(
    const u16* __restrict__ Aall, const u16* __restrict__ Btall,
    u16* __restrict__ hgout, float* __restrict__ out,
    const int* __restrict__ tok, const float* __restrict__ maxp,
    const int K, const int nt_per_e)
{
  const int bpe = 10 * nt_per_e;
  const int e = blockIdx.x / bpe;
  const int rem = blockIdx.x % bpe;
  const int m0 = (rem / nt_per_e) * 128, n0 = (rem % nt_per_e) * 128;
  const int N = nt_per_e * 128;

  const u16* Ae = Aall + (size_t)e * MPE * K;
  const u16* Be = Btall + (size_t)e * N * K;

  __shared__ __align__(16) u16 As[128 * 64];
  __shared__ __align__(16) u16 Bs[128 * 64];

  const int tid = threadIdx.x;
  const int wv = tid >> 6, l = tid & 63;
  const int wr = wv >> 1, wc = wv & 1;
  const int lr = l & 15, lk = l >> 4;

  f32x4 acc[4][4];
#pragma unroll
  for (int m = 0; m < 4; ++m)
#pragma unroll
    for (int n = 0; n < 4; ++n) acc[m][n] = (f32x4){0.f, 0.f, 0.f, 0.f};

  for (int kt = 0; kt < K; kt += 64) {
#pragma unroll
    for (int it = 0; it < 4; ++it) {
      const int gi = it * 256 + wv * 64 + l;
      const int row = gi >> 3, seg = gi & 7;
      gload16(Ae + (size_t)(m0 + row) * K + kt + seg * 8,
              (void*)(As + (size_t)(it * 256 + wv * 64) * 8));
      gload16(Be + (size_t)(n0 + row) * K + kt + seg * 8,
              (void*)(Bs + (size_t)(it * 256 + wv * 64) * 8));
    }
    __syncthreads();
#pragma unroll
    for (int kk = 0; kk < 2; ++kk) {
      bf16x8 af[4], bfr[4];
      const int ko = kk * 32 + lk * 8;
#pragma unroll
      for (int m = 0; m < 4; ++m)
        af[m] = *(const bf16x8*)&As[(wr * 64 + m * 16 + lr) * 64 + ko];
#pragma unroll
      for (int n = 0; n < 4; ++n)
        bfr[n] = *(const bf16x8*)&Bs[(wc * 64 + n * 16 + lr) * 64 + ko];
#pragma unroll
      for (int m = 0; m < 4; ++m)
#pragma unroll
        for (int n = 0; n < 4; ++n)
          acc[m][n] = __builtin_amdgcn_mfma_f32_16x16x32_bf16(
              af[m], bfr[n], acc[m][n], 0, 0, 0);
    }
    __syncthreads();
  }

  if (MODE == 1) {
#pragma unroll
    for (int m = 0; m < 4; ++m) {
#pragma unroll
      for (int r = 0; r < 4; ++r) {
        const int row = m0 + wr * 64 + m * 16 + lk * 4 + r;
        u16* hrow = hgout + ((size_t)e * MPE + row) * (size_t)N + n0;
#pragma unroll
        for (int n = 0; n < 4; ++n)
          hrow[wc * 64 + n * 16 + lr] = f2bf(fmaxf(acc[m][n][r], 0.0f));
      }
    }
  } else {
#pragma unroll
    for (int m = 0; m < 4; ++m) {
#pragma unroll
      for (int r = 0; r < 4; ++r) {
        const int rowg = m0 + wr * 64 + m * 16 + lk * 4 + r;
        const int b = rowg / CAP_, c = rowg % CAP_;
        const int t = tok[(b * E_ + e) * CAP_ + c];
        if (t >= 0) {
          const float sc = maxp[b * S_ + t];
          float* orow = out + ((size_t)(b * S_ + t)) * D_ + n0;
#pragma unroll
          for (int n = 0; n < 4; ++n)
            orow[wc * 64 + n * 16 + lr] = sc * acc[m][n][r];
        }
      }
    }
  }
}

// ---------------------------------------------------------------------------
extern "C" void kernel_launch(void* const* d_in, const int* in_sizes, int n_in,
                              void* d_out, int out_size, void* d_ws, size_t ws_size,
                              hipStream_t stream)
{
  const float* hs = (const float*)d_in[0];
  const float* rw = (const float*)d_in[1];
  const float* wi = (const float*)d_in[2];
  const float* wo = (const float*)d_in[3];

  float* out    = (float*)d_out;
  float* logits = out + (size_t)BS_ * D_;
  float* eout   = logits + (size_t)BS_ * E_;

  uint8_t* ws = (uint8_t*)d_ws;
  int*   tok  = (int*)(ws + 0);                 //   40,960 B
  float* maxp = (float*)(ws + 40960);           //   32,768 B
  int*   eidx = (int*)(ws + 73728);             //   32,768 B
  u16*   Xg   = (u16*)(ws + 131072);            // 20,971,520 B
  u16*   hg   = (u16*)(ws + 21102592);          // 83,886,080 B
  u16*   wT   = (u16*)(ws + 104988672);         // 67,108,864 B
  if (ws_size < 172097536ULL) return;           // ws too small: bail cleanly

  hipMemsetAsync(tok, 0xFF, 40960, stream);     // token slots = -1

  router_kernel<<<BS_ / 4, 256, 0, stream>>>(hs, rw, out, logits, maxp, eidx);
  scan_kernel<<<B_ * E_, 256, 0, stream>>>(eidx, tok, eout);
  transpose_kernel<<<E_ * (D_ / 32) * (F_ / 32), 256, 0, stream>>>(wi, wT, D_, F_);
  gather_kernel<<<E_ * MPE, 256, 0, stream>>>(hs, tok, Xg);
  moe_gemm<1><<<E_ * 10 * (F_ / 128), 256, 0, stream>>>(
      Xg, wT, hg, nullptr, tok, maxp, D_, F_ / 128);
  transpose_kernel<<<E_ * (F_ / 32) * (D_ / 32), 256, 0, stream>>>(wo, wT, F_, D_);
  moe_gemm<2><<<E_ * 10 * (D_ / 128), 256, 0, stream>>>(
      hg, wT, nullptr, out, tok, maxp, F_, D_ / 128);
}

// Round 2
// 340.263 us; speedup vs baseline: 1.3894x; 1.3894x over previous
//
#include <hip/hip_runtime.h>
#include <hip/hip_bf16.h>
#include <stdint.h>

#define B_ 4
#define S_ 2048
#define D_ 1024
#define F_ 4096
#define E_ 8
#define CAP_ 320
#define BS_ (B_*S_)      // 8192 tokens
#define MPE 1280         // B_*CAP_ rows per expert

typedef unsigned short u16;
typedef __attribute__((ext_vector_type(8))) short bf16x8;
typedef __attribute__((ext_vector_type(4))) float f32x4;
typedef __attribute__((ext_vector_type(4))) unsigned short u16x4;

__device__ __forceinline__ u16 f2bf(float f) {
  union { float f; uint32_t u; } v; v.f = f;
  uint32_t r = (v.u + 0x7FFFu + ((v.u >> 16) & 1u)) >> 16;
  return (u16)r;
}

__device__ __forceinline__ void gload16(const void* g, void* l) {
  __builtin_amdgcn_global_load_lds(
      (const __attribute__((address_space(1))) uint32_t*)g,
      (__attribute__((address_space(3))) uint32_t*)l, 16, 0, 0);
}

// ---------------------------------------------------------------------------
// Router: logits (f64 accum), softmax max-prob, argmax, and out = maxp * hs
// ---------------------------------------------------------------------------
__global__ __launch_bounds__(256) void router_kernel(
    const float* __restrict__ hs, const float* __restrict__ rw,
    float* __restrict__ out, float* __restrict__ logits,
    float* __restrict__ maxp, int* __restrict__ eidx)
{
  const int wv = threadIdx.x >> 6, l = threadIdx.x & 63;
  const int token = blockIdx.x * 4 + wv;
  const float* row = hs + (size_t)token * D_;
  const float4* rw4 = (const float4*)rw;

  double acc0=0, acc1=0, acc2=0, acc3=0, acc4=0, acc5=0, acc6=0, acc7=0;
  float4 v[4];
#pragma unroll
  for (int j = 0; j < 4; ++j) {
    const int d4 = l + j * 64;
    v[j] = ((const float4*)row)[d4];
#pragma unroll
    for (int c = 0; c < 4; ++c) {
      const int d = d4 * 4 + c;
      const float x = (&v[j].x)[c];
      const float4 w0 = rw4[d * 2];
      const float4 w1 = rw4[d * 2 + 1];
      acc0 += (double)x * (double)w0.x;
      acc1 += (double)x * (double)w0.y;
      acc2 += (double)x * (double)w0.z;
      acc3 += (double)x * (double)w0.w;
      acc4 += (double)x * (double)w1.x;
      acc5 += (double)x * (double)w1.y;
      acc6 += (double)x * (double)w1.z;
      acc7 += (double)x * (double)w1.w;
    }
  }
  double acc[E_] = {acc0, acc1, acc2, acc3, acc4, acc5, acc6, acc7};
#pragma unroll
  for (int e = 0; e < E_; ++e) {
#pragma unroll
    for (int off = 32; off; off >>= 1)
      acc[e] += __shfl_xor(acc[e], off);
  }
  float lg[E_];
#pragma unroll
  for (int e = 0; e < E_; ++e) lg[e] = (float)acc[e];

  float lmax = lg[0]; int am = 0;
#pragma unroll
  for (int e = 1; e < E_; ++e) { if (lg[e] > lmax) { lmax = lg[e]; am = e; } }
  float sum = 0.f;
#pragma unroll
  for (int e = 0; e < E_; ++e) sum += expf(lg[e] - lmax);
  const float mp = 1.0f / sum;

  float* orow = out + (size_t)token * D_;
#pragma unroll
  for (int j = 0; j < 4; ++j) {
    float4 o;
    o.x = v[j].x * mp; o.y = v[j].y * mp; o.z = v[j].z * mp; o.w = v[j].w * mp;
    ((float4*)orow)[l + j * 64] = o;
  }
  if (l == 0) {
#pragma unroll
    for (int e = 0; e < E_; ++e) logits[(size_t)token * E_ + e] = lg[e];
    maxp[token] = mp;
    eidx[token] = am;
  }
}

// ---------------------------------------------------------------------------
// Capacity scan: one block per (b,e)
// ---------------------------------------------------------------------------
__global__ __launch_bounds__(256) void scan_kernel(
    const int* __restrict__ eidx, int* __restrict__ tok,
    float* __restrict__ eout)
{
  const int b = blockIdx.x >> 3, e = blockIdx.x & 7;
  __shared__ int wsum[4];
  const int tid = threadIdx.x, wv = tid >> 6, l = tid & 63;
  int base = 0;
  for (int ch = 0; ch < S_ / 256; ++ch) {
    const int s = ch * 256 + tid;
    const bool p = (eidx[b * S_ + s] == e);
    const unsigned long long m = __ballot(p);
    const int lp = __popcll(m & ((1ULL << l) - 1ULL));
    if (l == 0) wsum[wv] = __popcll(m);
    __syncthreads();
    int pre = 0, tot = 0;
#pragma unroll
    for (int w = 0; w < 4; ++w) { if (w < wv) pre += wsum[w]; tot += wsum[w]; }
    if (p) {
      const int rank = base + pre + lp;
      if (rank < CAP_) tok[(b * E_ + e) * CAP_ + rank] = s;
      eout[b * S_ + s] = (rank < CAP_) ? (float)e : 0.0f;
    }
    base += tot;
    __syncthreads();
  }
}

// ---------------------------------------------------------------------------
// Transpose+convert: W[e][K][N] f32 -> WT[e][N][K] bf16
// ---------------------------------------------------------------------------
__global__ __launch_bounds__(256) void transpose_kernel(
    const float* __restrict__ W, u16* __restrict__ WT, int K, int N)
{
  __shared__ float tile[32][33];
  const int tiles_k = K >> 5, tiles_n = N >> 5;
  const int e = blockIdx.x / (tiles_k * tiles_n);
  const int r = blockIdx.x % (tiles_k * tiles_n);
  const int k0 = (r / tiles_n) << 5, n0 = (r % tiles_n) << 5;
  const int tx = threadIdx.x & 31, ty = threadIdx.x >> 5;
  const float* We = W + (size_t)e * K * N;
  u16* WTe = WT + (size_t)e * K * N;
#pragma unroll
  for (int i = 0; i < 4; ++i)
    tile[ty + i * 8][tx] = We[(size_t)(k0 + ty + i * 8) * N + (n0 + tx)];
  __syncthreads();
#pragma unroll
  for (int i = 0; i < 4; ++i) {
    const int n = n0 + ty + i * 8, k = k0 + tx;
    WTe[(size_t)n * K + k] = f2bf(tile[tx][ty + i * 8]);
  }
}

// ---------------------------------------------------------------------------
// Gather routed tokens -> Xg[e][b*CAP+c][D] bf16 (zeros for empty slots)
// ---------------------------------------------------------------------------
__global__ __launch_bounds__(256) void gather_kernel(
    const float* __restrict__ hs, const int* __restrict__ tok,
    u16* __restrict__ Xg)
{
  const int bx = blockIdx.x;
  const int e = bx / MPE, r = bx % MPE;
  const int b = r / CAP_, c = r % CAP_;
  const int t = tok[(b * E_ + e) * CAP_ + c];
  const int d = threadIdx.x * 4;
  u16x4 o;
  if (t >= 0) {
    const float4 vv = *(const float4*)(hs + ((size_t)(b * S_ + t)) * D_ + d);
    o[0] = f2bf(vv.x); o[1] = f2bf(vv.y); o[2] = f2bf(vv.z); o[3] = f2bf(vv.w);
  } else {
    o[0] = 0; o[1] = 0; o[2] = 0; o[3] = 0;
  }
  *(u16x4*)(Xg + (size_t)bx * D_ + d) = o;
}

// ---------------------------------------------------------------------------
// 256x256 8-phase grouped GEMM (T2 swizzle + T3/T4 counted vmcnt + T5 setprio)
// A[e][MPE][K] bf16, Bt[e][N][K] bf16. BK=64, 8 waves (2Mx4N), 512 thr.
// LDS per half-tile: [kk][row][32] bf16, st_16x32 XOR swizzle (byte b9->b5).
// MODE 1: hg = relu(A@B) -> bf16.  MODE 2: scatter out = maxp * (A@B).
// ---------------------------------------------------------------------------
template<int MODE>
__global__ __launch_bounds__(512, 2) void moe_gemm8(
    const u16* __restrict__ Aall, const u16* __restrict__ Btall,
    u16* __restrict__ hgout, float* __restrict__ out,
    const int* __restrict__ tok, const float* __restrict__ maxp,
    const int K, const int ntn)
{
  __shared__ __align__(16) u16 lds[2][2][2][8192]; // [buf][A/B][half] 128KiB

  const int nwg = gridDim.x;
  const int cpx = nwg >> 3;
  const int bid = blockIdx.x;
  const int swzb = (bid & 7) * cpx + (bid >> 3);   // XCD swizzle (nwg%8==0)
  const int bpe = 5 * ntn;
  const int e = swzb / bpe, rem = swzb % bpe;
  const int m0 = (rem / ntn) * 256, n0 = (rem % ntn) * 256;
  const int N = ntn * 256;

  const u16* Ae = Aall + (size_t)e * MPE * K;
  const u16* Be = Btall + (size_t)e * N * K;

  const int tid = threadIdx.x;
  const int wv = tid >> 6, l = tid & 63;
  const int wr = wv >> 2, wc = wv & 3;
  const int lr = l & 15, lk = l >> 4;
  const int rswz = ((lr >> 3) & 1) << 4;           // elem XOR for ds_read
  const int gs0 = tid ^ (((tid >> 5) & 1) << 1);   // inverse swizzle on source
  const size_t goff = (size_t)((gs0 >> 2) & 127) * K + (size_t)((gs0 & 3) * 8);
  const int dwoff = wv * 512;                      // wave-uniform LDS elems

  const u16* pA0 = Ae + (size_t)m0 * K;
  const u16* pA1 = Ae + (size_t)(m0 + 128) * K;
  const u16* pB0 = Be + (size_t)n0 * K;
  const u16* pB1 = Be + (size_t)(n0 + 128) * K;

  const int NT = K >> 6;

  f32x4 acc[8][4];
#pragma unroll
  for (int i = 0; i < 8; ++i)
#pragma unroll
    for (int j = 0; j < 4; ++j) acc[i][j] = (f32x4){0.f, 0.f, 0.f, 0.f};

  bf16x8 fa[8], fb0[4], fb1[4];

#define LDSH(p, ab, h) (&lds[p][ab][h][0])

#define STAGE(dhalf, rb, tt) do {                                          \
    const u16* s_ = (rb) + goff + (size_t)((tt) * 64);                     \
    gload16(s_,      (dhalf) + dwoff);                                     \
    gload16(s_ + 32, (dhalf) + 4096 + dwoff);                              \
  } while (0)

#define READ_A(msub, p) do {                                               \
    _Pragma("unroll")                                                      \
    for (int mf = 0; mf < 4; ++mf)                                         \
      _Pragma("unroll")                                                    \
      for (int kk = 0; kk < 2; ++kk)                                       \
        fa[mf*2+kk] = *(const bf16x8*)&lds[p][0][wr]                       \
            [(kk*128 + (msub)*64 + mf*16 + lr)*32 + ((lk*8) ^ rswz)];      \
  } while (0)

#define READ_B(nsub, p, fb) do {                                           \
    _Pragma("unroll")                                                      \
    for (int nf = 0; nf < 2; ++nf)                                         \
      _Pragma("unroll")                                                    \
      for (int kk = 0; kk < 2; ++kk)                                       \
        fb[nf*2+kk] = *(const bf16x8*)&lds[p][1][wc>>1]                    \
            [(kk*128 + (wc&1)*64 + (nsub)*32 + nf*16 + lr)*32              \
             + ((lk*8) ^ rswz)];                                           \
  } while (0)

#define MFMA_Q(msub, nsub, fb) do {                                        \
    __builtin_amdgcn_s_setprio(1);                                         \
    _Pragma("unroll")                                                      \
    for (int mf = 0; mf < 4; ++mf)                                         \
      _Pragma("unroll")                                                    \
      for (int nf = 0; nf < 2; ++nf)                                       \
        _Pragma("unroll")                                                  \
        for (int kk = 0; kk < 2; ++kk)                                     \
          acc[(msub)*4+mf][(nsub)*2+nf] =                                  \
              __builtin_amdgcn_mfma_f32_16x16x32_bf16(                     \
                  fa[mf*2+kk], fb[nf*2+kk],                                \
                  acc[(msub)*4+mf][(nsub)*2+nf], 0, 0, 0);                 \
    __builtin_amdgcn_s_setprio(0);                                         \
  } while (0)

#define BAR() __builtin_amdgcn_s_barrier()
#define LGKM0() do { asm volatile("s_waitcnt lgkmcnt(0)" ::: "memory");    \
                     __builtin_amdgcn_sched_barrier(0); } while (0)
#define VM4() asm volatile("s_waitcnt vmcnt(4)" ::: "memory")

#define DO_TILE(p, pn, tA, tB) do {                                        \
    /* s0 */                                                               \
    READ_A(0, p); READ_B(0, p, fb0);                                       \
    STAGE(LDSH(pn, 0, 0), pA0, (tA));                                      \
    BAR(); LGKM0();                                                        \
    MFMA_Q(0, 0, fb0);                                                     \
    BAR();                                                                 \
    /* s1 */                                                               \
    READ_B(1, p, fb1);                                                     \
    STAGE(LDSH(pn, 0, 1), pA1, (tA));                                      \
    BAR(); LGKM0();                                                        \
    MFMA_Q(0, 1, fb1);                                                     \
    BAR();                                                                 \
    /* s2 */                                                               \
    READ_A(1, p);                                                          \
    STAGE(LDSH(p, 1, 0), pB0, (tB));                                       \
    BAR(); LGKM0();                                                        \
    MFMA_Q(1, 0, fb0);                                                     \
    BAR();                                                                 \
    /* s3 */                                                               \
    STAGE(LDSH(p, 1, 1), pB1, (tB));                                       \
    BAR();                                                                 \
    MFMA_Q(1, 1, fb1);                                                     \
    VM4(); BAR();                                                          \
  } while (0)

  // Prologue: B(0), A(0), B(1) in steady-state age order
  STAGE(LDSH(0, 1, 0), pB0, 0);
  STAGE(LDSH(0, 1, 1), pB1, 0);
  STAGE(LDSH(0, 0, 0), pA0, 0);
  STAGE(LDSH(0, 0, 1), pA1, 0);
  STAGE(LDSH(1, 1, 0), pB0, 1);
  STAGE(LDSH(1, 1, 1), pB1, 1);
  VM4(); BAR();

  for (int t = 0; t < NT; t += 2) {
    const int tB0 = (t + 2 < NT) ? t + 2 : t;      // clamp: identical-bytes rewrite
    const int tB1 = (t + 3 < NT) ? t + 3 : t + 1;
    DO_TILE(0, 1, t + 1, tB0);
    DO_TILE(1, 0, tB0, tB1);
  }

  if (MODE == 1) {
#pragma unroll
    for (int i = 0; i < 8; ++i) {
#pragma unroll
      for (int r = 0; r < 4; ++r) {
        const int grow = m0 + wr * 128 + i * 16 + lk * 4 + r;
        u16* hrow = hgout + ((size_t)e * MPE + grow) * (size_t)N + n0 + wc * 64;
#pragma unroll
        for (int j = 0; j < 4; ++j)
          hrow[j * 16 + lr] = f2bf(fmaxf(acc[i][j][r], 0.0f));
      }
    }
  } else {
#pragma unroll
    for (int i = 0; i < 8; ++i) {
#pragma unroll
      for (int r = 0; r < 4; ++r) {
        const int grow = m0 + wr * 128 + i * 16 + lk * 4 + r;
        const int b = grow / CAP_, c = grow % CAP_;
        const int t = tok[(b * E_ + e) * CAP_ + c];
        if (t >= 0) {
          const float sc = maxp[b * S_ + t];
          float* orow = out + ((size_t)(b * S_ + t)) * D_ + n0 + wc * 64;
#pragma unroll
          for (int j = 0; j < 4; ++j)
            orow[j * 16 + lr] = sc * acc[i][j][r];
        }
      }
    }
  }
#undef LDSH
#undef STAGE
#undef READ_A
#undef READ_B
#undef MFMA_Q
#undef BAR
#undef LGKM0
#undef VM4
#undef DO_TILE
}

// ---------------------------------------------------------------------------
extern "C" void kernel_launch(void* const* d_in, const int* in_sizes, int n_in,
                              void* d_out, int out_size, void* d_ws, size_t ws_size,
                              hipStream_t stream)
{
  const float* hs = (const float*)d_in[0];
  const float* rw = (const float*)d_in[1];
  const float* wi = (const float*)d_in[2];
  const float* wo = (const float*)d_in[3];

  float* out    = (float*)d_out;
  float* logits = out + (size_t)BS_ * D_;
  float* eout   = logits + (size_t)BS_ * E_;

  uint8_t* ws = (uint8_t*)d_ws;
  int*   tok  = (int*)(ws + 0);                 //   40,960 B
  float* maxp = (float*)(ws + 40960);           //   32,768 B
  int*   eidx = (int*)(ws + 73728);             //   32,768 B
  u16*   Xg   = (u16*)(ws + 131072);            // 20,971,520 B
  u16*   hg   = (u16*)(ws + 21102592);          // 83,886,080 B
  u16*   wT   = (u16*)(ws + 104988672);         // 67,108,864 B
  if (ws_size < 172097536ULL) return;

  hipMemsetAsync(tok, 0xFF, 40960, stream);

  router_kernel<<<BS_ / 4, 256, 0, stream>>>(hs, rw, out, logits, maxp, eidx);
  scan_kernel<<<B_ * E_, 256, 0, stream>>>(eidx, tok, eout);
  transpose_kernel<<<E_ * (D_ / 32) * (F_ / 32), 256, 0, stream>>>(wi, wT, D_, F_);
  gather_kernel<<<E_ * MPE, 256, 0, stream>>>(hs, tok, Xg);
  moe_gemm8<1><<<E_ * 5 * (F_ / 256), 512, 0, stream>>>(
      Xg, wT, hg, nullptr, tok, maxp, D_, F_ / 256);       // 640 blocks
  transpose_kernel<<<E_ * (F_ / 32) * (D_ / 32), 256, 0, stream>>>(wo, wT, F_, D_);
  moe_gemm8<2><<<E_ * 5 * (D_ / 256), 512, 0, stream>>>(
      hg, wT, nullptr, out, tok, maxp, F_, D_ / 256);      // 160 blocks
}